// Round 1
// baseline (460.939 us; speedup 1.0000x reference)
//
#include <hip/hip_runtime.h>

#define BATCH 8
#define C     64
#define H     128
#define WD    128
#define C3    192
#define HW    (H*WD)
#define PW    130         // padded H/W for conv input
#define ICS   192         // channel stride in inT2 (channel-last)
#define STR   72          // attn LDS row stride in shorts
#define CBUF  (4*PW*64)   // conv stage buffer: 4 rows x 130 gx x 64 c (shorts)

typedef __attribute__((ext_vector_type(8))) short short8;
typedef __attribute__((ext_vector_type(4))) float f32x4;
typedef unsigned short ushort_t;

__device__ __forceinline__ unsigned short f2bf(float f) {
    unsigned u = __builtin_bit_cast(unsigned, f);
    u += 0x7fffu + ((u >> 16) & 1u);
    return (unsigned short)(u >> 16);
}
__device__ __forceinline__ int pack2(unsigned short lo, unsigned short hi) {
    return (int)(((unsigned)hi << 16) | (unsigned)lo);
}

// ===========================================================================
// compose_kernel: fold Wx into Wx1/Wx2; pack 5 weight mats to bf16 + biases.
// ===========================================================================
__global__ __launch_bounds__(256) void compose_kernel(
    const float* __restrict__ Wx,  const float* __restrict__ bx,
    const float* __restrict__ Wx1, const float* __restrict__ bx1,
    const float* __restrict__ Wx2, const float* __restrict__ bx2,
    const float* __restrict__ Wxf, const float* __restrict__ bxf,
    const float* __restrict__ Wxr, const float* __restrict__ bxr,
    ushort_t* __restrict__ Wall, float* __restrict__ ball)
{
    int t = threadIdx.x;
    int o = t & 63, cq = t >> 6;
    for (int c = cq*16; c < cq*16 + 16; ++c) {
        Wall[0*4096 + o*64 + c] = f2bf(Wx [o*64 + c]);
        Wall[3*4096 + o*64 + c] = f2bf(Wxf[o*64 + c]);
        Wall[4*4096 + o*64 + c] = f2bf(Wxr[o*64 + c]);
        float a1 = 0.f, a2 = 0.f;
        for (int k = 0; k < 64; ++k) {
            float wc = Wx[k*64 + c];
            a1 += Wx1[o*64 + k] * wc;
            a2 += Wx2[o*64 + k] * wc;
        }
        Wall[1*4096 + o*64 + c] = f2bf(a1);
        Wall[2*4096 + o*64 + c] = f2bf(a2);
    }
    if (cq == 0) {
        ball[0*64 + o] = bx[o];
        ball[3*64 + o] = bxf[o];
        ball[4*64 + o] = bxr[o];
        float b1 = bx1[o], b2 = bx2[o];
        for (int k = 0; k < 64; ++k) {
            b1 += Wx1[o*64 + k] * bx[k];
            b2 += Wx2[o*64 + k] * bx[k];
        }
        ball[1*64 + o] = b1;
        ball[2*64 + o] = b2;
    }
}

// ===========================================================================
// attn_mfma: one block per (b,h), 256 threads = 4 waves (unchanged from R3).
// ===========================================================================
__global__ __launch_bounds__(256, 4) void attn_mfma(
    const float* __restrict__ x, const float* __restrict__ xf, const float* __restrict__ xr,
    const ushort_t* __restrict__ Wall, const float* __restrict__ ball,
    ushort_t* __restrict__ inT2)
{
    __shared__ ushort_t lds[4*64*STR];
    ushort_t* P = lds;
    ushort_t* Q = lds + 64*STR;
    ushort_t* R = lds + 2*64*STR;
    ushort_t* T = lds + 3*64*STR;

    const int t = threadIdx.x;
    const int wv = t >> 6, lane = t & 63, m = lane & 15, quad = lane >> 4;
    const int b = blockIdx.x >> 7, h = blockIdx.x & 127;
    const float* xs  = x  + (size_t)b*C*HW + (size_t)h*WD;
    const float* xfs = xf + (size_t)b*C*HW + (size_t)h*WD;
    const float* xrs = xr + (size_t)b*C*HW + (size_t)h*WD;

    auto stage = [&](const float* src, int wc, ushort_t* dst) {
        int c = t >> 2, wq = (t & 3) << 4;
        const float* p = src + (size_t)c*HW + wc + wq;
        float4 v0 = *(const float4*)(p);
        float4 v1 = *(const float4*)(p + 4);
        float4 v2 = *(const float4*)(p + 8);
        float4 v3 = *(const float4*)(p + 12);
        float vv[16] = {v0.x,v0.y,v0.z,v0.w, v1.x,v1.y,v1.z,v1.w,
                        v2.x,v2.y,v2.z,v2.w, v3.x,v3.y,v3.z,v3.w};
#pragma unroll
        for (int j = 0; j < 16; ++j) dst[(wq + j)*STR + c] = f2bf(vv[j]);
    };
    auto projB = [&](const ushort_t* src, const ushort_t* W, const float* bias,
                     ushort_t* dst) {
        int mt = wv;
#pragma unroll
        for (int nt = 0; nt < 4; ++nt) {
            f32x4 acc = {0.f,0.f,0.f,0.f};
#pragma unroll
            for (int k = 0; k < 2; ++k) {
                short8 a  = *(const short8*)(src + (mt*16 + m)*STR + k*32 + quad*8);
                short8 bb = *(const short8*)(W   + (nt*16 + m)*64  + k*32 + quad*8);
                acc = __builtin_amdgcn_mfma_f32_16x16x32_bf16(a, bb, acc, 0,0,0);
            }
            float bo = bias[nt*16 + m];
            int o = nt*16 + m, w0 = mt*16 + quad*4;
            *(int*)(dst + o*STR + w0)     = pack2(f2bf(acc[0]+bo), f2bf(acc[1]+bo));
            *(int*)(dst + o*STR + w0 + 2) = pack2(f2bf(acc[2]+bo), f2bf(acc[3]+bo));
        }
    };
    auto projA = [&](const ushort_t* src, const ushort_t* W, const float* bias,
                     ushort_t* dstT) {
        int mt = wv;
        float b4[4];
#pragma unroll
        for (int r = 0; r < 4; ++r) b4[r] = bias[mt*16 + quad*4 + r];
#pragma unroll
        for (int nt = 0; nt < 4; ++nt) {
            f32x4 acc = {0.f,0.f,0.f,0.f};
#pragma unroll
            for (int k = 0; k < 2; ++k) {
                short8 a  = *(const short8*)(W   + (mt*16 + m)*64  + k*32 + quad*8);
                short8 bb = *(const short8*)(src + (nt*16 + m)*STR + k*32 + quad*8);
                acc = __builtin_amdgcn_mfma_f32_16x16x32_bf16(a, bb, acc, 0,0,0);
            }
            int w = nt*16 + m, o0 = mt*16 + quad*4;
            *(int*)(dstT + w*STR + o0)     = pack2(f2bf(acc[0]+b4[0]), f2bf(acc[1]+b4[1]));
            *(int*)(dstT + w*STR + o0 + 2) = pack2(f2bf(acc[2]+b4[2]), f2bf(acc[3]+b4[3]));
        }
    };
    auto scoreStep = [&](const ushort_t* A, const ushort_t* B, f32x4* sc) {
        int mt = wv;
#pragma unroll
        for (int nt = 0; nt < 4; ++nt)
#pragma unroll
            for (int k = 0; k < 2; ++k) {
                short8 a  = *(const short8*)(A + (mt*16 + m)*STR + k*32 + quad*8);
                short8 bb = *(const short8*)(B + (nt*16 + m)*STR + k*32 + quad*8);
                sc[nt] = __builtin_amdgcn_mfma_f32_16x16x32_bf16(a, bb, sc[nt], 0,0,0);
            }
    };
    auto scoreDump = [&](const f32x4* sc, ushort_t* dst) {
        int c0 = wv*16 + quad*4;
#pragma unroll
        for (int nt = 0; nt < 4; ++nt) {
            int d = nt*16 + m;
#pragma unroll
            for (int r = 0; r < 4; ++r) dst[(c0 + r)*STR + d] = f2bf(sc[nt][r]);
        }
    };
    auto feat = [&](const ushort_t* Sc, const ushort_t* XpT, ushort_t* stg) {
        int mt = wv;
#pragma unroll
        for (int nt = 0; nt < 4; ++nt) {
            f32x4 acc = {0.f,0.f,0.f,0.f};
#pragma unroll
            for (int k = 0; k < 2; ++k) {
                short8 a  = *(const short8*)(Sc  + (mt*16 + m)*STR + k*32 + quad*8);
                short8 bb = *(const short8*)(XpT + (nt*16 + m)*STR + k*32 + quad*8);
                acc = __builtin_amdgcn_mfma_f32_16x16x32_bf16(a, bb, acc, 0,0,0);
            }
            int w = nt*16 + m, c0 = mt*16 + quad*4;
            *(int*)(stg + w*STR + c0)     = pack2(f2bf(acc[0]), f2bf(acc[1]));
            *(int*)(stg + w*STR + c0 + 2) = pack2(f2bf(acc[2]), f2bf(acc[3]));
        }
    };
    auto emitBr = [&](const ushort_t* stg, int wc, int coff) {
#pragma unroll
        for (int it = 0; it < 2; ++it) {
            int j = it*256 + t;
            int row = j >> 3, seg = j & 7;
            int v[4];
#pragma unroll
            for (int k = 0; k < 4; ++k) v[k] = *(const int*)(stg + row*STR + seg*8 + k*2);
            ushort_t* dst = inT2 + (((size_t)b*PW + h + 1)*PW + (wc + 1 + row))*ICS
                                 + coff + seg*8;
            *(int4*)dst = make_int4(v[0], v[1], v[2], v[3]);
        }
    };

    const ushort_t* W0 = Wall;            const float* b0 = ball;
    const ushort_t* W1 = Wall + 4096;     const float* b1 = ball + 64;
    const ushort_t* W2 = Wall + 2*4096;   const float* b2 = ball + 128;
    const ushort_t* W3 = Wall + 3*4096;   const float* b3 = ball + 192;
    const ushort_t* W4 = Wall + 4*4096;   const float* b4 = ball + 256;

    f32x4 sc1[4], sc2[4];
#pragma unroll
    for (int i = 0; i < 4; ++i) { sc1[i] = (f32x4){0,0,0,0}; sc2[i] = (f32x4){0,0,0,0}; }

    for (int wc = 0; wc < WD; wc += 64) {
        stage(xs, wc, P);            __syncthreads();
        projB(P, W1, b1, R);         stage(xfs, wc, Q);   __syncthreads();
        projB(Q, W3, b3, T);         __syncthreads();
        scoreStep(R, T, sc1);        stage(xrs, wc, Q);   __syncthreads();
        projB(P, W2, b2, R);         projB(Q, W4, b4, T); __syncthreads();
        scoreStep(R, T, sc2);        __syncthreads();
    }

    scoreDump(sc1, P);  scoreDump(sc2, R);  __syncthreads();
    for (int wc = 0; wc < WD; wc += 64) {
        stage(xs, wc, Q);            __syncthreads();
        projA(Q, W0, b0, T);         __syncthreads();
        feat(P, T, Q);               __syncthreads();
        emitBr(Q, wc, 0);            __syncthreads();
        feat(R, T, Q);               __syncthreads();
        emitBr(Q, wc, 64);           __syncthreads();
    }
}

// ===========================================================================
// prep kernel: x -> inT2[...][128..191] bf16 (channel-last) + zero all halos.
// ===========================================================================
__global__ __launch_bounds__(256) void prep_kernel(const float* __restrict__ x,
                                                   ushort_t* __restrict__ inT2)
{
    int b  = blockIdx.x / PW, py = blockIdx.x % PW;
    int t  = threadIdx.x;
    ushort_t* rowp = inT2 + ((size_t)b*PW + py)*(size_t)PW*ICS;

    if (py == 0 || py == PW-1) {
        int4 z = make_int4(0,0,0,0);
        for (int j = t; j < PW*ICS/8; j += 256) ((int4*)rowp)[j] = z;
        return;
    }
    if (t < 48) {
        int side = t / 24, seg = t % 24;
        ((int4*)(rowp + (size_t)(side ? (PW-1) : 0)*ICS))[seg] = make_int4(0,0,0,0);
    }
    __shared__ ushort_t sx[128*72];
    int y = py - 1;
    for (int k = t; k < 64*128; k += 256) {
        int c = k >> 7, xx = k & 127;
        sx[xx*72 + c] = f2bf(x[((size_t)b*C + c)*HW + (size_t)y*WD + xx]);
    }
    __syncthreads();
    for (int j = t; j < 128*8; j += 256) {
        int xx = j >> 3, seg = j & 7;
        *(int4*)(rowp + (size_t)(xx+1)*ICS + 128 + seg*8) = *(const int4*)(sx + xx*72 + seg*8);
    }
}

// ===========================================================================
// weight pack for conv: W_msa -> Wpack[otile][tap*6+icc][lane][8] bf16.
// ===========================================================================
__global__ __launch_bounds__(256) void pack_kernel(const float* __restrict__ W,
                                                   ushort_t* __restrict__ Wpk)
{
    int k = blockIdx.x*256 + threadIdx.x;
    if (k >= 12*54*64) return;
    int lane = k & 63, os = k >> 6;
    int otile = os / 54, s = os % 54;
    int tap = s / 6, icc = s % 6;
    int o   = otile*16 + (lane & 15);
    int ic0 = icc*32 + (lane >> 4)*8;
    ushort_t v[8];
#pragma unroll
    for (int j = 0; j < 8; ++j)
        v[j] = f2bf(W[(size_t)(o*C3 + ic0 + j)*9 + tap]);
    *(int4*)(Wpk + (size_t)k*8) = *(const int4*)v;
}

// ===========================================================================
// conv v3: producer-consumer implicit-GEMM bf16 MFMA.
// Block = (b, y-pair), 512 threads = 8 waves: waves 0..5 compute
// (og=wv>>1 owns 4 o-tiles, yi=wv&1 owns a row), waves 6..7 produce.
// LDS: double buffer [4 rows][130 gx][64 c] bf16 = 2 x 66,560 B (gfx950 160KB).
// Producers stage chunk k+1 via global_load_lds while consumers crunch chunk k
// (per-wave vmcnt -> no cross-wave drains). A-granules XOR-swizzled by gx&7
// (applied on the producer's GLOBAL address; LDS side stays uniform+lane*16)
// -> conflict-free ds_read_b128. Epilogue stages BN+ReLU rows in LDS then
// writes full 512B lines.
// ===========================================================================
__global__ __launch_bounds__(512, 2) void conv_mfma(
    const ushort_t* __restrict__ inT2, const ushort_t* __restrict__ Wpk,
    const float* __restrict__ bias, const float* __restrict__ gamma,
    const float* __restrict__ beta, const float* __restrict__ mean,
    const float* __restrict__ var,  float* __restrict__ out)
{
    __shared__ ushort_t sA[2*CBUF];            // 133,120 B

    const int t = threadIdx.x;
    const int wv = t >> 6, lane = t & 63;
    const int m = lane & 15, quad = lane >> 4;
    const int b  = blockIdx.x >> 6, y0 = (blockIdx.x & 63)*2;
    const int yi = wv & 1, og = wv >> 1;       // compute waves: og 0..2

    f32x4 acc[32];                              // [j][xt] -> acc[j*8+xt]
#pragma unroll
    for (int i = 0; i < 32; ++i) acc[i] = (f32x4){0.f,0.f,0.f,0.f};

    // ---- producer: stage 64-c chunk into buffer (4160 16B slots, 128 lanes)
    auto produce = [&](int ch, int bufi) {
        ushort_t* dst = sA + bufi*CBUF;
        const int ic0 = ch*64;
        const int pt = t - 384;                // wave 6 -> 0..63, wave 7 -> 64..127
        for (int i = 0; i < 32; ++i) {
            int sl = i*128 + pt;
            int wi = sl & 7, rowgx = sl >> 3;
            int row = rowgx / PW, gx = rowgx - row*PW;
            int wl = wi ^ (gx & 7);            // granule swizzle (global side)
            const ushort_t* g = inT2 + (((size_t)b*PW + y0 + row)*PW + gx)*ICS
                                     + ic0 + wl*8;
            __builtin_amdgcn_global_load_lds(
                (const __attribute__((address_space(1))) unsigned int*)g,
                (__attribute__((address_space(3))) unsigned int*)(dst + (size_t)sl*8),
                16, 0, 0);
        }
        if (pt < 64) {
            int sl = 4096 + pt;
            int wi = sl & 7, rowgx = sl >> 3;
            int row = rowgx / PW, gx = rowgx - row*PW;
            int wl = wi ^ (gx & 7);
            const ushort_t* g = inT2 + (((size_t)b*PW + y0 + row)*PW + gx)*ICS
                                     + ic0 + wl*8;
            __builtin_amdgcn_global_load_lds(
                (const __attribute__((address_space(1))) unsigned int*)g,
                (__attribute__((address_space(3))) unsigned int*)(dst + (size_t)sl*8),
                16, 0, 0);
        }
    };

    // ---- consumer: one 64-c chunk = 9 taps x 8 xt x 2 k x 4 o-tiles ----
    auto compute = [&](int ch, int bufi) {
        const ushort_t* src = sA + bufi*CBUF;
        short8 bf[8], bfn[8];
#pragma unroll
        for (int j = 0; j < 4; ++j)
#pragma unroll
            for (int k = 0; k < 2; ++k)
                bf[j*2+k] = *(const short8*)(Wpk +
                    (((size_t)(og*4+j)*54 + ch*2 + k)*64 + lane)*8);
#pragma unroll
        for (int tap = 0; tap < 9; ++tap) {
            if (tap < 8) {
#pragma unroll
                for (int j = 0; j < 4; ++j)
#pragma unroll
                    for (int k = 0; k < 2; ++k)
                        bfn[j*2+k] = *(const short8*)(Wpk +
                            (((size_t)(og*4+j)*54 + (tap+1)*6 + ch*2 + k)*64 + lane)*8);
            }
            const int ky = tap/3, kx = tap - ky*3;
            const int sw = (kx + m) & 7;
            const int rowb = ((yi + ky)*PW + kx + m)*64;
            const int g0 = (quad ^ sw)*8, g1 = ((quad+4) ^ sw)*8;
#pragma unroll
            for (int xt = 0; xt < 8; ++xt) {
                short8 af0 = *(const short8*)(src + rowb + xt*1024 + g0);
                short8 af1 = *(const short8*)(src + rowb + xt*1024 + g1);
#pragma unroll
                for (int j = 0; j < 4; ++j) {
                    acc[j*8+xt] = __builtin_amdgcn_mfma_f32_16x16x32_bf16(af0, bf[j*2],   acc[j*8+xt], 0,0,0);
                    acc[j*8+xt] = __builtin_amdgcn_mfma_f32_16x16x32_bf16(af1, bf[j*2+1], acc[j*8+xt], 0,0,0);
                }
            }
#pragma unroll
            for (int q = 0; q < 8; ++q) bf[q] = bfn[q];
        }
    };

    // ---- pipeline: 3 chunks of 64 c, producers one chunk ahead ----
    if (wv >= 6) produce(0, 0);
    __syncthreads();
    for (int ch = 0; ch < 3; ++ch) {
        if (wv >= 6) { if (ch < 2) produce(ch + 1, (ch + 1) & 1); }
        else          compute(ch, ch & 1);
        __syncthreads();
    }

    // ---- epilogue: BN+ReLU -> LDS stage -> full-line stores ----
    float* sOut = (float*)sA;                  // 192 x 132 f32 = 101,376 B
    for (int y = 0; y < 2; ++y) {
        if (wv < 6 && yi == y) {
#pragma unroll
            for (int j = 0; j < 4; ++j) {
                int o = (og*4 + j)*16 + m;
                float A  = gamma[o] * rsqrtf(var[o] + 1e-4f);
                float Bv = (bias[o] - mean[o])*A + beta[o];
#pragma unroll
                for (int xt = 0; xt < 8; ++xt) {
                    f32x4 a4 = acc[j*8 + xt];
                    *(float4*)(sOut + o*132 + xt*16 + quad*4) =
                        make_float4(fmaxf(a4[0]*A + Bv, 0.f), fmaxf(a4[1]*A + Bv, 0.f),
                                    fmaxf(a4[2]*A + Bv, 0.f), fmaxf(a4[3]*A + Bv, 0.f));
                }
            }
        }
        __syncthreads();
#pragma unroll
        for (int i = 0; i < 12; ++i) {
            int s = i*512 + t;                 // 6144 float4 slots
            int o = s >> 5, xs4 = (s & 31)*4;
            float4 v = *(const float4*)(sOut + o*132 + xs4);
            *(float4*)(out + (((size_t)b*C3 + o)*H + y0 + y)*WD + xs4) = v;
        }
        __syncthreads();
    }
}

extern "C" void kernel_launch(void* const* d_in, const int* in_sizes, int n_in,
                              void* d_out, int out_size, void* d_ws, size_t ws_size,
                              hipStream_t stream)
{
    const float* x   = (const float*)d_in[0];
    const float* xf  = (const float*)d_in[1];
    const float* xr  = (const float*)d_in[2];
    const float* Wx  = (const float*)d_in[3];
    const float* bx  = (const float*)d_in[4];
    const float* Wx1 = (const float*)d_in[5];
    const float* bx1 = (const float*)d_in[6];
    const float* Wx2 = (const float*)d_in[7];
    const float* bx2 = (const float*)d_in[8];
    const float* Wxf = (const float*)d_in[9];
    const float* bxf = (const float*)d_in[10];
    const float* Wxr = (const float*)d_in[11];
    const float* bxr = (const float*)d_in[12];
    const float* Wm  = (const float*)d_in[13];
    const float* bms = (const float*)d_in[14];
    const float* gam = (const float*)d_in[15];
    const float* bet = (const float*)d_in[16];
    const float* mea = (const float*)d_in[17];
    const float* va  = (const float*)d_in[18];
    (void)in_sizes; (void)n_in; (void)out_size; (void)ws_size;

    // ws layout: inT2 (B,130,130,192) bf16 @ 0 (51,916,800 B);
    //            conv Wpack @ 52,000,000 (663,552 B);
    //            attn Wall bf16 @ 52,700,000; ball f32 @ 52,750,000.
    ushort_t* inT2 = (ushort_t*)d_ws;
    ushort_t* Wpk  = (ushort_t*)((char*)d_ws + 52000000);
    ushort_t* Wall = (ushort_t*)((char*)d_ws + 52700000);
    float*    ball = (float*)   ((char*)d_ws + 52750000);
    float* outp = (float*)d_out;

    compose_kernel<<<dim3(1), dim3(256), 0, stream>>>(
        Wx, bx, Wx1, bx1, Wx2, bx2, Wxf, bxf, Wxr, bxr, Wall, ball);
    pack_kernel<<<dim3(162), dim3(256), 0, stream>>>(Wm, Wpk);
    prep_kernel<<<dim3(BATCH*PW), dim3(256), 0, stream>>>(x, inT2);
    attn_mfma<<<dim3(BATCH*H), dim3(256), 0, stream>>>(
        x, xf, xr, Wall, ball, inT2);
    conv_mfma<<<dim3(BATCH*64), dim3(512), 0, stream>>>(
        inT2, Wpk, bms, gam, bet, mea, va, outp);
}

// Round 2
// 398.744 us; speedup vs baseline: 1.1560x; 1.1560x over previous
//
#include <hip/hip_runtime.h>

#define BATCH 8
#define C     64
#define H     128
#define WD    128
#define C3    192
#define HW    (H*WD)
#define PW    130         // padded H/W for conv input
#define ICS   192         // channel stride in inT2 (channel-last)
#define CBUF  (4*PW*64)   // conv stage buffer: 4 rows x 130 gx x 64 c (shorts)

// attn LDS tiles: 64 rows x 64 cols, granule-XOR swizzled, no pad.
#define SWZ(r) ((((r) & 7) ^ (((r) >> 3) & 6)))

typedef __attribute__((ext_vector_type(8))) short short8;
typedef __attribute__((ext_vector_type(4))) float f32x4;
typedef unsigned short ushort_t;

__device__ __forceinline__ unsigned short f2bf(float f) {
    unsigned u = __builtin_bit_cast(unsigned, f);
    u += 0x7fffu + ((u >> 16) & 1u);
    return (unsigned short)(u >> 16);
}
__device__ __forceinline__ int pack2(unsigned short lo, unsigned short hi) {
    return (int)(((unsigned)hi << 16) | (unsigned)lo);
}

// ===========================================================================
// compose_kernel: fold Wx into Wx1/Wx2; pack 5 weight mats to bf16 + biases.
// Parallelized: 64 blocks (one per output row o) x 64 threads (one per c).
// ===========================================================================
__global__ __launch_bounds__(64) void compose_kernel(
    const float* __restrict__ Wx,  const float* __restrict__ bx,
    const float* __restrict__ Wx1, const float* __restrict__ bx1,
    const float* __restrict__ Wx2, const float* __restrict__ bx2,
    const float* __restrict__ Wxf, const float* __restrict__ bxf,
    const float* __restrict__ Wxr, const float* __restrict__ bxr,
    ushort_t* __restrict__ Wall, float* __restrict__ ball)
{
    int o = blockIdx.x;      // 0..63
    int c = threadIdx.x;     // 0..63
    Wall[0*4096 + o*64 + c] = f2bf(Wx [o*64 + c]);
    Wall[3*4096 + o*64 + c] = f2bf(Wxf[o*64 + c]);
    Wall[4*4096 + o*64 + c] = f2bf(Wxr[o*64 + c]);
    float a1 = 0.f, a2 = 0.f;
    for (int k = 0; k < 64; ++k) {
        float wc = Wx[k*64 + c];          // coalesced across lanes
        a1 += Wx1[o*64 + k] * wc;         // scalar broadcast
        a2 += Wx2[o*64 + k] * wc;
    }
    Wall[1*4096 + o*64 + c] = f2bf(a1);
    Wall[2*4096 + o*64 + c] = f2bf(a2);
    // biases: lane-parallel partial products + wave reduce
    float t1 = Wx1[o*64 + c] * bx[c];
    float t2 = Wx2[o*64 + c] * bx[c];
    for (int off = 32; off; off >>= 1) {
        t1 += __shfl_down(t1, off);
        t2 += __shfl_down(t2, off);
    }
    if (c == 0) {
        ball[0*64 + o] = bx[o];
        ball[1*64 + o] = bx1[o] + t1;
        ball[2*64 + o] = bx2[o] + t2;
        ball[3*64 + o] = bxf[o];
        ball[4*64 + o] = bxr[o];
    }
}

// ===========================================================================
// attn_mfma v2: one block per (b,h), 256 threads = 4 waves.
//  - x is read as bf16 channel-last from inT2 (written by prep_kernel):
//    identical bits to f2bf(x), no fp32 re-read, no scalar transpose.
//  - 4 LDS tiles 64x64 (8KB each, 32KB total), granule-XOR swizzle
//    SWZ(row) = (row&7)^((row>>3)&6): <=2-way banks on every access
//    (read needs row bits 0-2 spread; transposed write needs bits 4-5).
//  - loop1: 4 barriers/chunk (merged independent phases).
// ===========================================================================
__global__ __launch_bounds__(256, 4) void attn_mfma(
    const float* __restrict__ xf, const float* __restrict__ xr,
    const ushort_t* __restrict__ Wall, const float* __restrict__ ball,
    ushort_t* inT2)
{
    __shared__ ushort_t lds[4*4096];
    ushort_t* P = lds;
    ushort_t* Q = lds + 4096;
    ushort_t* R = lds + 2*4096;
    ushort_t* T = lds + 3*4096;

    const int t = threadIdx.x;
    const int wv = t >> 6, lane = t & 63, m = lane & 15, quad = lane >> 4;
    const int b = blockIdx.x >> 7, h = blockIdx.x & 127;
    const float* xfs = xf + (size_t)b*C*HW + (size_t)h*WD;
    const float* xrs = xr + (size_t)b*C*HW + (size_t)h*WD;
    const size_t rowbase = ((size_t)b*PW + h + 1)*PW;   // inT2 pixel row base

    // ---- stage x from inT2 (bf16 channel-last) into tile [w][c] ----
    auto stageX = [&](ushort_t* dst, int wc) {
#pragma unroll
        for (int it = 0; it < 2; ++it) {
            int slot = it*256 + t;               // 512 slots of 16B
            int w = slot >> 3, seg = slot & 7;
            const ushort_t* src = inT2 + (rowbase + (wc + 1 + w))*ICS + 128 + seg*8;
            *(int4*)(dst + w*64 + ((seg ^ SWZ(w)) << 3)) = *(const int4*)src;
        }
    };
    // ---- stage fp32 source, transposed, into tile [w][c] (swizzled cols) ----
    auto stageF = [&](const float* src, int wc, ushort_t* dst) {
        int c = t >> 2, wq = (t & 3) << 4;
        const float* p = src + (size_t)c*HW + wc + wq;
        float4 v0 = *(const float4*)(p);
        float4 v1 = *(const float4*)(p + 4);
        float4 v2 = *(const float4*)(p + 8);
        float4 v3 = *(const float4*)(p + 12);
        float vv[16] = {v0.x,v0.y,v0.z,v0.w, v1.x,v1.y,v1.z,v1.w,
                        v2.x,v2.y,v2.z,v2.w, v3.x,v3.y,v3.z,v3.w};
        int cg = c >> 3, cl = c & 7;
#pragma unroll
        for (int j = 0; j < 16; ++j) {
            int row = wq + j;
            dst[row*64 + ((cg ^ SWZ(row)) << 3) + cl] = f2bf(vv[j]);
        }
    };
    auto projB = [&](const ushort_t* src, const ushort_t* W, const float* bias,
                     ushort_t* dst) {
        int mt = wv;
        int arow = mt*16 + m;
        int sa = SWZ(arow);
#pragma unroll
        for (int nt = 0; nt < 4; ++nt) {
            f32x4 acc = {0.f,0.f,0.f,0.f};
#pragma unroll
            for (int k = 0; k < 2; ++k) {
                short8 a  = *(const short8*)(src + arow*64 + (((4*k+quad) ^ sa) << 3));
                short8 bb = *(const short8*)(W   + (nt*16 + m)*64  + k*32 + quad*8);
                acc = __builtin_amdgcn_mfma_f32_16x16x32_bf16(a, bb, acc, 0,0,0);
            }
            float bo = bias[nt*16 + m];
            int o = nt*16 + m, w0 = mt*16 + quad*4;
            int base = o*64 + (((w0 >> 3) ^ SWZ(o)) << 3) + (w0 & 7);
            *(int*)(dst + base)     = pack2(f2bf(acc[0]+bo), f2bf(acc[1]+bo));
            *(int*)(dst + base + 2) = pack2(f2bf(acc[2]+bo), f2bf(acc[3]+bo));
        }
    };
    auto projA = [&](const ushort_t* src, const ushort_t* W, const float* bias,
                     ushort_t* dstT) {
        int mt = wv;
        float b4[4];
#pragma unroll
        for (int r = 0; r < 4; ++r) b4[r] = bias[mt*16 + quad*4 + r];
#pragma unroll
        for (int nt = 0; nt < 4; ++nt) {
            f32x4 acc = {0.f,0.f,0.f,0.f};
            int brow = nt*16 + m;
            int sb = SWZ(brow);
#pragma unroll
            for (int k = 0; k < 2; ++k) {
                short8 a  = *(const short8*)(W   + (mt*16 + m)*64  + k*32 + quad*8);
                short8 bb = *(const short8*)(src + brow*64 + (((4*k+quad) ^ sb) << 3));
                acc = __builtin_amdgcn_mfma_f32_16x16x32_bf16(a, bb, acc, 0,0,0);
            }
            int w = nt*16 + m, o0 = mt*16 + quad*4;
            int base = w*64 + (((o0 >> 3) ^ SWZ(w)) << 3) + (o0 & 7);
            *(int*)(dstT + base)     = pack2(f2bf(acc[0]+b4[0]), f2bf(acc[1]+b4[1]));
            *(int*)(dstT + base + 2) = pack2(f2bf(acc[2]+b4[2]), f2bf(acc[3]+b4[3]));
        }
    };
    auto scoreStep = [&](const ushort_t* A, const ushort_t* B, f32x4* sc) {
        int mt = wv;
        int arow = mt*16 + m;
        int sa = SWZ(arow);
#pragma unroll
        for (int nt = 0; nt < 4; ++nt) {
            int brow = nt*16 + m;
            int sb = SWZ(brow);
#pragma unroll
            for (int k = 0; k < 2; ++k) {
                short8 a  = *(const short8*)(A + arow*64 + (((4*k+quad) ^ sa) << 3));
                short8 bb = *(const short8*)(B + brow*64 + (((4*k+quad) ^ sb) << 3));
                sc[nt] = __builtin_amdgcn_mfma_f32_16x16x32_bf16(a, bb, sc[nt], 0,0,0);
            }
        }
    };
    auto scoreDump = [&](const f32x4* sc, ushort_t* dst) {
        int c0 = wv*16 + quad*4;
#pragma unroll
        for (int nt = 0; nt < 4; ++nt) {
            int d = nt*16 + m;
            int gd = d >> 3, dl = d & 7;
#pragma unroll
            for (int r = 0; r < 4; ++r) {
                int row = c0 + r;
                dst[row*64 + ((gd ^ SWZ(row)) << 3) + dl] = f2bf(sc[nt][r]);
            }
        }
    };
    auto feat = [&](const ushort_t* Sc, const ushort_t* XpT, ushort_t* stg) {
        int mt = wv;
        int arow = mt*16 + m;
        int sa = SWZ(arow);
#pragma unroll
        for (int nt = 0; nt < 4; ++nt) {
            f32x4 acc = {0.f,0.f,0.f,0.f};
            int brow = nt*16 + m;
            int sb = SWZ(brow);
#pragma unroll
            for (int k = 0; k < 2; ++k) {
                short8 a  = *(const short8*)(Sc  + arow*64 + (((4*k+quad) ^ sa) << 3));
                short8 bb = *(const short8*)(XpT + brow*64 + (((4*k+quad) ^ sb) << 3));
                acc = __builtin_amdgcn_mfma_f32_16x16x32_bf16(a, bb, acc, 0,0,0);
            }
            int w = nt*16 + m, c0 = mt*16 + quad*4;
            int base = w*64 + (((c0 >> 3) ^ SWZ(w)) << 3) + (c0 & 7);
            *(int*)(stg + base)     = pack2(f2bf(acc[0]), f2bf(acc[1]));
            *(int*)(stg + base + 2) = pack2(f2bf(acc[2]), f2bf(acc[3]));
        }
    };
    auto emitBr = [&](const ushort_t* stg, int wc, int coff) {
#pragma unroll
        for (int it = 0; it < 2; ++it) {
            int j = it*256 + t;
            int row = j >> 3, seg = j & 7;
            int4 v = *(const int4*)(stg + row*64 + ((seg ^ SWZ(row)) << 3));
            ushort_t* dst = inT2 + (rowbase + (wc + 1 + row))*ICS + coff + seg*8;
            *(int4*)dst = v;
        }
    };

    const ushort_t* W0 = Wall;            const float* b0 = ball;
    const ushort_t* W1 = Wall + 4096;     const float* b1 = ball + 64;
    const ushort_t* W2 = Wall + 2*4096;   const float* b2 = ball + 128;
    const ushort_t* W3 = Wall + 3*4096;   const float* b3 = ball + 192;
    const ushort_t* W4 = Wall + 4*4096;   const float* b4 = ball + 256;

    f32x4 sc1[4], sc2[4];
#pragma unroll
    for (int i = 0; i < 4; ++i) { sc1[i] = (f32x4){0,0,0,0}; sc2[i] = (f32x4){0,0,0,0}; }

    // ---- loop 1: scores (4 barriers per 64-col chunk) ----
    stageX(P, 0); stageF(xfs, 0, Q);
    __syncthreads();
    for (int wc = 0; wc < WD; wc += 64) {
        projB(P, W1, b1, R);  projB(Q, W3, b3, T);
        __syncthreads();
        scoreStep(R, T, sc1); stageF(xrs, wc, Q);
        __syncthreads();
        projB(P, W2, b2, R);  projB(Q, W4, b4, T);
        __syncthreads();
        scoreStep(R, T, sc2);
        if (wc == 0) { stageX(P, 64); stageF(xfs, 64, Q); }
        __syncthreads();
    }

    // ---- loop 2: features. X/XT ping-pong between Q and T ----
    scoreDump(sc1, P);  scoreDump(sc2, R);  stageX(Q, 0);
    __syncthreads();
    int pp = 0;
    for (int wc = 0; wc < WD; wc += 64, pp ^= 1) {
        ushort_t* X  = pp ? T : Q;
        ushort_t* XT = pp ? Q : T;
        projA(X, W0, b0, XT);
        __syncthreads();
        feat(P, XT, X);
        __syncthreads();
        emitBr(X, wc, 0);
        __syncthreads();
        feat(R, XT, X);
        __syncthreads();
        emitBr(X, wc, 64);
        if (wc == 0) stageX(T, 64);
        __syncthreads();
    }
}

// ===========================================================================
// prep kernel: x -> inT2[...][128..191] bf16 (channel-last) + zero all halos.
// ===========================================================================
__global__ __launch_bounds__(256) void prep_kernel(const float* __restrict__ x,
                                                   ushort_t* __restrict__ inT2)
{
    int b  = blockIdx.x / PW, py = blockIdx.x % PW;
    int t  = threadIdx.x;
    ushort_t* rowp = inT2 + ((size_t)b*PW + py)*(size_t)PW*ICS;

    if (py == 0 || py == PW-1) {
        int4 z = make_int4(0,0,0,0);
        for (int j = t; j < PW*ICS/8; j += 256) ((int4*)rowp)[j] = z;
        return;
    }
    if (t < 48) {
        int side = t / 24, seg = t % 24;
        ((int4*)(rowp + (size_t)(side ? (PW-1) : 0)*ICS))[seg] = make_int4(0,0,0,0);
    }
    __shared__ ushort_t sx[128*72];
    int y = py - 1;
    for (int k = t; k < 64*128; k += 256) {
        int c = k >> 7, xx = k & 127;
        sx[xx*72 + c] = f2bf(x[((size_t)b*C + c)*HW + (size_t)y*WD + xx]);
    }
    __syncthreads();
    for (int j = t; j < 128*8; j += 256) {
        int xx = j >> 3, seg = j & 7;
        *(int4*)(rowp + (size_t)(xx+1)*ICS + 128 + seg*8) = *(const int4*)(sx + xx*72 + seg*8);
    }
}

// ===========================================================================
// weight pack for conv: W_msa -> Wpack[otile][tap*6+icc][lane][8] bf16.
// ===========================================================================
__global__ __launch_bounds__(256) void pack_kernel(const float* __restrict__ W,
                                                   ushort_t* __restrict__ Wpk)
{
    int k = blockIdx.x*256 + threadIdx.x;
    if (k >= 12*54*64) return;
    int lane = k & 63, os = k >> 6;
    int otile = os / 54, s = os % 54;
    int tap = s / 6, icc = s % 6;
    int o   = otile*16 + (lane & 15);
    int ic0 = icc*32 + (lane >> 4)*8;
    ushort_t v[8];
#pragma unroll
    for (int j = 0; j < 8; ++j)
        v[j] = f2bf(W[(size_t)(o*C3 + ic0 + j)*9 + tap]);
    *(int4*)(Wpk + (size_t)k*8) = *(const int4*)v;
}

// ===========================================================================
// conv v3: producer-consumer implicit-GEMM bf16 MFMA. (unchanged)
// ===========================================================================
__global__ __launch_bounds__(512, 2) void conv_mfma(
    const ushort_t* __restrict__ inT2, const ushort_t* __restrict__ Wpk,
    const float* __restrict__ bias, const float* __restrict__ gamma,
    const float* __restrict__ beta, const float* __restrict__ mean,
    const float* __restrict__ var,  float* __restrict__ out)
{
    __shared__ ushort_t sA[2*CBUF];            // 133,120 B

    const int t = threadIdx.x;
    const int wv = t >> 6, lane = t & 63;
    const int m = lane & 15, quad = lane >> 4;
    const int b  = blockIdx.x >> 6, y0 = (blockIdx.x & 63)*2;
    const int yi = wv & 1, og = wv >> 1;       // compute waves: og 0..2

    f32x4 acc[32];                              // [j][xt] -> acc[j*8+xt]
#pragma unroll
    for (int i = 0; i < 32; ++i) acc[i] = (f32x4){0.f,0.f,0.f,0.f};

    // ---- producer: stage 64-c chunk into buffer (4160 16B slots, 128 lanes)
    auto produce = [&](int ch, int bufi) {
        ushort_t* dst = sA + bufi*CBUF;
        const int ic0 = ch*64;
        const int pt = t - 384;                // wave 6 -> 0..63, wave 7 -> 64..127
        for (int i = 0; i < 32; ++i) {
            int sl = i*128 + pt;
            int wi = sl & 7, rowgx = sl >> 3;
            int row = rowgx / PW, gx = rowgx - row*PW;
            int wl = wi ^ (gx & 7);            // granule swizzle (global side)
            const ushort_t* g = inT2 + (((size_t)b*PW + y0 + row)*PW + gx)*ICS
                                     + ic0 + wl*8;
            __builtin_amdgcn_global_load_lds(
                (const __attribute__((address_space(1))) unsigned int*)g,
                (__attribute__((address_space(3))) unsigned int*)(dst + (size_t)sl*8),
                16, 0, 0);
        }
        if (pt < 64) {
            int sl = 4096 + pt;
            int wi = sl & 7, rowgx = sl >> 3;
            int row = rowgx / PW, gx = rowgx - row*PW;
            int wl = wi ^ (gx & 7);
            const ushort_t* g = inT2 + (((size_t)b*PW + y0 + row)*PW + gx)*ICS
                                     + ic0 + wl*8;
            __builtin_amdgcn_global_load_lds(
                (const __attribute__((address_space(1))) unsigned int*)g,
                (__attribute__((address_space(3))) unsigned int*)(dst + (size_t)sl*8),
                16, 0, 0);
        }
    };

    // ---- consumer: one 64-c chunk = 9 taps x 8 xt x 2 k x 4 o-tiles ----
    auto compute = [&](int ch, int bufi) {
        const ushort_t* src = sA + bufi*CBUF;
        short8 bf[8], bfn[8];
#pragma unroll
        for (int j = 0; j < 4; ++j)
#pragma unroll
            for (int k = 0; k < 2; ++k)
                bf[j*2+k] = *(const short8*)(Wpk +
                    (((size_t)(og*4+j)*54 + ch*2 + k)*64 + lane)*8);
#pragma unroll
        for (int tap = 0; tap < 9; ++tap) {
            if (tap < 8) {
#pragma unroll
                for (int j = 0; j < 4; ++j)
#pragma unroll
                    for (int k = 0; k < 2; ++k)
                        bfn[j*2+k] = *(const short8*)(Wpk +
                            (((size_t)(og*4+j)*54 + (tap+1)*6 + ch*2 + k)*64 + lane)*8);
            }
            const int ky = tap/3, kx = tap - ky*3;
            const int sw = (kx + m) & 7;
            const int rowb = ((yi + ky)*PW + kx + m)*64;
            const int g0 = (quad ^ sw)*8, g1 = ((quad+4) ^ sw)*8;
#pragma unroll
            for (int xt = 0; xt < 8; ++xt) {
                short8 af0 = *(const short8*)(src + rowb + xt*1024 + g0);
                short8 af1 = *(const short8*)(src + rowb + xt*1024 + g1);
#pragma unroll
                for (int j = 0; j < 4; ++j) {
                    acc[j*8+xt] = __builtin_amdgcn_mfma_f32_16x16x32_bf16(af0, bf[j*2],   acc[j*8+xt], 0,0,0);
                    acc[j*8+xt] = __builtin_amdgcn_mfma_f32_16x16x32_bf16(af1, bf[j*2+1], acc[j*8+xt], 0,0,0);
                }
            }
#pragma unroll
            for (int q = 0; q < 8; ++q) bf[q] = bfn[q];
        }
    };

    // ---- pipeline: 3 chunks of 64 c, producers one chunk ahead ----
    if (wv >= 6) produce(0, 0);
    __syncthreads();
    for (int ch = 0; ch < 3; ++ch) {
        if (wv >= 6) { if (ch < 2) produce(ch + 1, (ch + 1) & 1); }
        else          compute(ch, ch & 1);
        __syncthreads();
    }

    // ---- epilogue: BN+ReLU -> LDS stage -> full-line stores ----
    float* sOut = (float*)sA;                  // 192 x 132 f32 = 101,376 B
    for (int y = 0; y < 2; ++y) {
        if (wv < 6 && yi == y) {
#pragma unroll
            for (int j = 0; j < 4; ++j) {
                int o = (og*4 + j)*16 + m;
                float A  = gamma[o] * rsqrtf(var[o] + 1e-4f);
                float Bv = (bias[o] - mean[o])*A + beta[o];
#pragma unroll
                for (int xt = 0; xt < 8; ++xt) {
                    f32x4 a4 = acc[j*8 + xt];
                    *(float4*)(sOut + o*132 + xt*16 + quad*4) =
                        make_float4(fmaxf(a4[0]*A + Bv, 0.f), fmaxf(a4[1]*A + Bv, 0.f),
                                    fmaxf(a4[2]*A + Bv, 0.f), fmaxf(a4[3]*A + Bv, 0.f));
                }
            }
        }
        __syncthreads();
#pragma unroll
        for (int i = 0; i < 12; ++i) {
            int s = i*512 + t;                 // 6144 float4 slots
            int o = s >> 5, xs4 = (s & 31)*4;
            float4 v = *(const float4*)(sOut + o*132 + xs4);
            *(float4*)(out + (((size_t)b*C3 + o)*H + y0 + y)*WD + xs4) = v;
        }
        __syncthreads();
    }
}

extern "C" void kernel_launch(void* const* d_in, const int* in_sizes, int n_in,
                              void* d_out, int out_size, void* d_ws, size_t ws_size,
                              hipStream_t stream)
{
    const float* x   = (const float*)d_in[0];
    const float* xf  = (const float*)d_in[1];
    const float* xr  = (const float*)d_in[2];
    const float* Wx  = (const float*)d_in[3];
    const float* bx  = (const float*)d_in[4];
    const float* Wx1 = (const float*)d_in[5];
    const float* bx1 = (const float*)d_in[6];
    const float* Wx2 = (const float*)d_in[7];
    const float* bx2 = (const float*)d_in[8];
    const float* Wxf = (const float*)d_in[9];
    const float* bxf = (const float*)d_in[10];
    const float* Wxr = (const float*)d_in[11];
    const float* bxr = (const float*)d_in[12];
    const float* Wm  = (const float*)d_in[13];
    const float* bms = (const float*)d_in[14];
    const float* gam = (const float*)d_in[15];
    const float* bet = (const float*)d_in[16];
    const float* mea = (const float*)d_in[17];
    const float* va  = (const float*)d_in[18];
    (void)in_sizes; (void)n_in; (void)out_size; (void)ws_size;

    // ws layout: inT2 (B,130,130,192) bf16 @ 0 (51,916,800 B);
    //            conv Wpack @ 52,000,000 (663,552 B);
    //            attn Wall bf16 @ 52,700,000; ball f32 @ 52,750,000.
    ushort_t* inT2 = (ushort_t*)d_ws;
    ushort_t* Wpk  = (ushort_t*)((char*)d_ws + 52000000);
    ushort_t* Wall = (ushort_t*)((char*)d_ws + 52700000);
    float*    ball = (float*)   ((char*)d_ws + 52750000);
    float* outp = (float*)d_out;

    compose_kernel<<<dim3(64), dim3(64), 0, stream>>>(
        Wx, bx, Wx1, bx1, Wx2, bx2, Wxf, bxf, Wxr, bxr, Wall, ball);
    pack_kernel<<<dim3(162), dim3(256), 0, stream>>>(Wm, Wpk);
    prep_kernel<<<dim3(BATCH*PW), dim3(256), 0, stream>>>(x, inT2);
    attn_mfma<<<dim3(BATCH*H), dim3(256), 0, stream>>>(
        xf, xr, Wall, ball, inT2);
    conv_mfma<<<dim3(BATCH*64), dim3(512), 0, stream>>>(
        inT2, Wpk, bms, gam, bet, mea, va, outp);
}

// Round 3
// 371.482 us; speedup vs baseline: 1.2408x; 1.0734x over previous
//
#include <hip/hip_runtime.h>

#define BATCH 8
#define C     64
#define H     128
#define WD    128
#define C3    192
#define HW    (H*WD)
#define PW    130         // padded H/W for conv input
#define CBUF  (4*PW*64)   // conv stage buffer: 4 rows x 130 gx x 64 c (shorts)

// attn LDS tiles: 64 rows x 64 cols, granule-XOR swizzled, no pad.
#define SWZ(r) ((((r) & 7) ^ (((r) >> 3) & 6)))

typedef __attribute__((ext_vector_type(8))) short short8;
typedef __attribute__((ext_vector_type(4))) float f32x4;
typedef unsigned short ushort_t;

__device__ __forceinline__ unsigned short f2bf(float f) {
    unsigned u = __builtin_bit_cast(unsigned, f);
    u += 0x7fffu + ((u >> 16) & 1u);
    return (unsigned short)(u >> 16);
}
__device__ __forceinline__ int pack2(unsigned short lo, unsigned short hi) {
    return (int)(((unsigned)hi << 16) | (unsigned)lo);
}

// ===========================================================================
// compose_kernel: fold Wx into Wx1/Wx2; pack 5 weight mats to bf16 + biases.
// 64 blocks (one per output row o) x 64 threads (one per c).
// ===========================================================================
__global__ __launch_bounds__(64) void compose_kernel(
    const float* __restrict__ Wx,  const float* __restrict__ bx,
    const float* __restrict__ Wx1, const float* __restrict__ bx1,
    const float* __restrict__ Wx2, const float* __restrict__ bx2,
    const float* __restrict__ Wxf, const float* __restrict__ bxf,
    const float* __restrict__ Wxr, const float* __restrict__ bxr,
    ushort_t* __restrict__ Wall, float* __restrict__ ball)
{
    int o = blockIdx.x;      // 0..63
    int c = threadIdx.x;     // 0..63
    Wall[0*4096 + o*64 + c] = f2bf(Wx [o*64 + c]);
    Wall[3*4096 + o*64 + c] = f2bf(Wxf[o*64 + c]);
    Wall[4*4096 + o*64 + c] = f2bf(Wxr[o*64 + c]);
    float a1 = 0.f, a2 = 0.f;
    for (int k = 0; k < 64; ++k) {
        float wc = Wx[k*64 + c];          // coalesced across lanes
        a1 += Wx1[o*64 + k] * wc;         // scalar broadcast
        a2 += Wx2[o*64 + k] * wc;
    }
    Wall[1*4096 + o*64 + c] = f2bf(a1);
    Wall[2*4096 + o*64 + c] = f2bf(a2);
    float t1 = Wx1[o*64 + c] * bx[c];
    float t2 = Wx2[o*64 + c] * bx[c];
    for (int off = 32; off; off >>= 1) {
        t1 += __shfl_down(t1, off);
        t2 += __shfl_down(t2, off);
    }
    if (c == 0) {
        ball[0*64 + o] = bx[o];
        ball[1*64 + o] = bx1[o] + t1;
        ball[2*64 + o] = bx2[o] + t2;
        ball[3*64 + o] = bxf[o];
        ball[4*64 + o] = bxr[o];
    }
}

// ===========================================================================
// prep v3: x -> xcl (B,PW,PW,64) with halos; xf -> xfT, xr -> xrT
// (B,128,128,64) dense bf16 channel-last; zero halos of feat+xcl.
// ===========================================================================
__global__ __launch_bounds__(256) void prep_kernel(
    const float* __restrict__ x, const float* __restrict__ xf,
    const float* __restrict__ xr,
    ushort_t* __restrict__ xcl, ushort_t* __restrict__ feat,
    ushort_t* __restrict__ xfT, ushort_t* __restrict__ xrT)
{
    int b  = blockIdx.x / PW, py = blockIdx.x % PW;
    int t  = threadIdx.x;
    const size_t prow = ((size_t)b*PW + py)*PW;   // pixel row base

    if (py == 0 || py == PW-1) {
        int4 z = make_int4(0,0,0,0);
        for (int j = t; j < PW*128/8; j += 256) ((int4*)(feat + prow*128))[j] = z;
        for (int j = t; j < PW*64/8;  j += 256) ((int4*)(xcl  + prow*64 ))[j] = z;
        return;
    }
    if (t < 48) {
        int4 z = make_int4(0,0,0,0);
        if (t < 32) {
            int side = t >> 4, seg = t & 15;
            *(int4*)(feat + (prow + (side ? PW-1 : 0))*128 + seg*8) = z;
        } else {
            int u = t - 32, side = u >> 3, seg = u & 7;
            *(int4*)(xcl + (prow + (side ? PW-1 : 0))*64 + seg*8) = z;
        }
    }
    __shared__ ushort_t sx[128*72];
    const int y = py - 1;

    // --- x -> xcl (with halo offset) ---
    for (int k = t; k < 64*128; k += 256) {
        int c = k >> 7, xx = k & 127;
        sx[xx*72 + c] = f2bf(x[((size_t)b*C + c)*HW + (size_t)y*WD + xx]);
    }
    __syncthreads();
    for (int j = t; j < 128*8; j += 256) {
        int xx = j >> 3, seg = j & 7;
        *(int4*)(xcl + (prow + xx + 1)*64 + seg*8) = *(const int4*)(sx + xx*72 + seg*8);
    }
    __syncthreads();
    // --- xf -> xfT (dense) ---
    for (int k = t; k < 64*128; k += 256) {
        int c = k >> 7, xx = k & 127;
        sx[xx*72 + c] = f2bf(xf[((size_t)b*C + c)*HW + (size_t)y*WD + xx]);
    }
    __syncthreads();
    for (int j = t; j < 128*8; j += 256) {
        int xx = j >> 3, seg = j & 7;
        *(int4*)(xfT + (((size_t)b*128 + y)*128 + xx)*64 + seg*8) = *(const int4*)(sx + xx*72 + seg*8);
    }
    __syncthreads();
    // --- xr -> xrT (dense) ---
    for (int k = t; k < 64*128; k += 256) {
        int c = k >> 7, xx = k & 127;
        sx[xx*72 + c] = f2bf(xr[((size_t)b*C + c)*HW + (size_t)y*WD + xx]);
    }
    __syncthreads();
    for (int j = t; j < 128*8; j += 256) {
        int xx = j >> 3, seg = j & 7;
        *(int4*)(xrT + (((size_t)b*128 + y)*128 + xx)*64 + seg*8) = *(const int4*)(sx + xx*72 + seg*8);
    }
}

// ===========================================================================
// attn_mfma v3: one block per (b,h), 256 threads = 4 waves.
// All inputs pre-transposed bf16 channel-last; staging = pure int4 copies.
// 6 LDS buffers (48 KB): loop1 3 phases/chunk, loop2 3 phases/chunk.
// Writes planar feat surface (256 B/pixel written as two adjacent halves).
// ===========================================================================
__global__ __launch_bounds__(256, 3) void attn_mfma(
    const ushort_t* __restrict__ xcl, const ushort_t* __restrict__ xfT,
    const ushort_t* __restrict__ xrT,
    const ushort_t* __restrict__ Wall, const float* __restrict__ ball,
    ushort_t* __restrict__ feat)
{
    __shared__ ushort_t lds[6*4096];
    ushort_t* P = lds;            // buffer roles rotate; see phase comments
    ushort_t* Q = lds + 4096;
    ushort_t* U = lds + 2*4096;
    ushort_t* R = lds + 3*4096;
    ushort_t* V = lds + 4*4096;
    ushort_t* T = lds + 5*4096;

    const int t = threadIdx.x;
    const int wv = t >> 6, lane = t & 63, m = lane & 15, quad = lane >> 4;
    const int b = blockIdx.x >> 7, h = blockIdx.x & 127;
    const size_t rowbase = ((size_t)b*PW + h + 1)*PW;          // xcl/feat pixels
    const ushort_t* xrow  = xcl + (rowbase + 1)*64;            // interior pixel 0
    const ushort_t* xfrow = xfT + ((size_t)b*128 + h)*128*64;
    const ushort_t* xrrow = xrT + ((size_t)b*128 + h)*128*64;

    // stage a 64-pixel x 64-ch bf16 tile (pixel stride 64 shorts) into LDS
    auto stageT = [&](const ushort_t* base, ushort_t* dst) {
#pragma unroll
        for (int it = 0; it < 2; ++it) {
            int slot = it*256 + t;               // 512 slots of 16B
            int w = slot >> 3, seg = slot & 7;
            *(int4*)(dst + w*64 + ((seg ^ SWZ(w)) << 3)) =
                *(const int4*)(base + w*64 + seg*8);
        }
    };
    auto projB = [&](const ushort_t* src, const ushort_t* W, const float* bias,
                     ushort_t* dst) {
        int arow = wv*16 + m;
        int sa = SWZ(arow);
#pragma unroll
        for (int nt = 0; nt < 4; ++nt) {
            f32x4 acc = {0.f,0.f,0.f,0.f};
#pragma unroll
            for (int k = 0; k < 2; ++k) {
                short8 a  = *(const short8*)(src + arow*64 + (((4*k+quad) ^ sa) << 3));
                short8 bb = *(const short8*)(W   + (nt*16 + m)*64  + k*32 + quad*8);
                acc = __builtin_amdgcn_mfma_f32_16x16x32_bf16(a, bb, acc, 0,0,0);
            }
            float bo = bias[nt*16 + m];
            int o = nt*16 + m, w0 = wv*16 + quad*4;
            int base = o*64 + (((w0 >> 3) ^ SWZ(o)) << 3) + (w0 & 7);
            *(int*)(dst + base)     = pack2(f2bf(acc[0]+bo), f2bf(acc[1]+bo));
            *(int*)(dst + base + 2) = pack2(f2bf(acc[2]+bo), f2bf(acc[3]+bo));
        }
    };
    auto projA = [&](const ushort_t* src, const ushort_t* W, const float* bias,
                     ushort_t* dstT) {
        float b4[4];
#pragma unroll
        for (int r = 0; r < 4; ++r) b4[r] = bias[wv*16 + quad*4 + r];
#pragma unroll
        for (int nt = 0; nt < 4; ++nt) {
            f32x4 acc = {0.f,0.f,0.f,0.f};
            int brow = nt*16 + m;
            int sb = SWZ(brow);
#pragma unroll
            for (int k = 0; k < 2; ++k) {
                short8 a  = *(const short8*)(W   + (wv*16 + m)*64  + k*32 + quad*8);
                short8 bb = *(const short8*)(src + brow*64 + (((4*k+quad) ^ sb) << 3));
                acc = __builtin_amdgcn_mfma_f32_16x16x32_bf16(a, bb, acc, 0,0,0);
            }
            int w = nt*16 + m, o0 = wv*16 + quad*4;
            int base = w*64 + (((o0 >> 3) ^ SWZ(w)) << 3) + (o0 & 7);
            *(int*)(dstT + base)     = pack2(f2bf(acc[0]+b4[0]), f2bf(acc[1]+b4[1]));
            *(int*)(dstT + base + 2) = pack2(f2bf(acc[2]+b4[2]), f2bf(acc[3]+b4[3]));
        }
    };
    auto scoreStep = [&](const ushort_t* A, const ushort_t* B, f32x4* sc) {
        int arow = wv*16 + m;
        int sa = SWZ(arow);
#pragma unroll
        for (int nt = 0; nt < 4; ++nt) {
            int brow = nt*16 + m;
            int sb = SWZ(brow);
#pragma unroll
            for (int k = 0; k < 2; ++k) {
                short8 a  = *(const short8*)(A + arow*64 + (((4*k+quad) ^ sa) << 3));
                short8 bb = *(const short8*)(B + brow*64 + (((4*k+quad) ^ sb) << 3));
                sc[nt] = __builtin_amdgcn_mfma_f32_16x16x32_bf16(a, bb, sc[nt], 0,0,0);
            }
        }
    };
    auto scoreDump = [&](const f32x4* sc, ushort_t* dst) {
        int c0 = wv*16 + quad*4;
#pragma unroll
        for (int nt = 0; nt < 4; ++nt) {
            int d = nt*16 + m;
            int gd = d >> 3, dl = d & 7;
#pragma unroll
            for (int r = 0; r < 4; ++r) {
                int row = c0 + r;
                dst[row*64 + ((gd ^ SWZ(row)) << 3) + dl] = f2bf(sc[nt][r]);
            }
        }
    };
    auto featF = [&](const ushort_t* Sc, const ushort_t* XpT, ushort_t* stg) {
        int arow = wv*16 + m;
        int sa = SWZ(arow);
#pragma unroll
        for (int nt = 0; nt < 4; ++nt) {
            f32x4 acc = {0.f,0.f,0.f,0.f};
            int brow = nt*16 + m;
            int sb = SWZ(brow);
#pragma unroll
            for (int k = 0; k < 2; ++k) {
                short8 a  = *(const short8*)(Sc  + arow*64 + (((4*k+quad) ^ sa) << 3));
                short8 bb = *(const short8*)(XpT + brow*64 + (((4*k+quad) ^ sb) << 3));
                acc = __builtin_amdgcn_mfma_f32_16x16x32_bf16(a, bb, acc, 0,0,0);
            }
            int w = nt*16 + m, c0 = wv*16 + quad*4;
            int base = w*64 + (((c0 >> 3) ^ SWZ(w)) << 3) + (c0 & 7);
            *(int*)(stg + base)     = pack2(f2bf(acc[0]), f2bf(acc[1]));
            *(int*)(stg + base + 2) = pack2(f2bf(acc[2]), f2bf(acc[3]));
        }
    };
    auto emitPair = [&](const ushort_t* O1, const ushort_t* O2, int wc) {
#pragma unroll
        for (int it = 0; it < 4; ++it) {
            int j = (it & 1)*256 + t;
            const ushort_t* S = (it < 2) ? O1 : O2;
            int half = (it < 2) ? 0 : 64;
            int row = j >> 3, seg = j & 7;
            int4 v = *(const int4*)(S + row*64 + ((seg ^ SWZ(row)) << 3));
            *(int4*)(feat + (rowbase + wc + 1 + row)*128 + half + seg*8) = v;
        }
    };

    const ushort_t* W0 = Wall;            const float* b0 = ball;
    const ushort_t* W1 = Wall + 4096;     const float* b1 = ball + 64;
    const ushort_t* W2 = Wall + 2*4096;   const float* b2 = ball + 128;
    const ushort_t* W3 = Wall + 3*4096;   const float* b3 = ball + 192;
    const ushort_t* W4 = Wall + 4*4096;   const float* b4 = ball + 256;

    f32x4 sc1[4], sc2[4];
#pragma unroll
    for (int i = 0; i < 4; ++i) { sc1[i] = (f32x4){0,0,0,0}; sc2[i] = (f32x4){0,0,0,0}; }

    // ================= loop 1: scores (3 phases/chunk) =================
    stageT(xrow, P); stageT(xfrow, Q); stageT(xrrow, U);
    __syncthreads();
    // chunk 0: x=P, xf=Q, xr=U
    projB(P, W1, b1, R);  projB(P, W2, b2, V);  projB(Q, W3, b3, T);
    __syncthreads();
    scoreStep(R, T, sc1); projB(U, W4, b4, Q);
    __syncthreads();
    scoreStep(V, Q, sc2);
    stageT(xrow + 64*64, P); stageT(xfrow + 64*64, T); stageT(xrrow + 64*64, U);
    __syncthreads();
    // chunk 1: x=P, xf=T, xr=U
    projB(P, W1, b1, R);  projB(P, W2, b2, V);  projB(T, W3, b3, Q);
    __syncthreads();
    scoreStep(R, Q, sc1); projB(U, W4, b4, T);
    __syncthreads();
    scoreStep(V, T, sc2);
    stageT(xrow, P);                       // x chunk0 again for loop 2
    __syncthreads();

    // ================= loop 2: features (3 phases/chunk) =================
    scoreDump(sc1, Q);  scoreDump(sc2, U);
    __syncthreads();
    // chunk 0: X=P -> XT=R; outputs P,T; prefetch x64 -> V
    projA(P, W0, b0, R);
    __syncthreads();
    featF(Q, R, P);  featF(U, R, T);  stageT(xrow + 64*64, V);
    __syncthreads();
    emitPair(P, T, 0);
    __syncthreads();
    // chunk 1: X=V -> XT=R; outputs V,T
    projA(V, W0, b0, R);
    __syncthreads();
    featF(Q, R, V);  featF(U, R, T);
    __syncthreads();
    emitPair(V, T, 64);
}

// ===========================================================================
// weight pack for conv: W_msa -> Wpack[otile][tap*6+icc][lane][8] bf16.
// ===========================================================================
__global__ __launch_bounds__(256) void pack_kernel(const float* __restrict__ W,
                                                   ushort_t* __restrict__ Wpk)
{
    int k = blockIdx.x*256 + threadIdx.x;
    if (k >= 12*54*64) return;
    int lane = k & 63, os = k >> 6;
    int otile = os / 54, s = os % 54;
    int tap = s / 6, icc = s % 6;
    int o   = otile*16 + (lane & 15);
    int ic0 = icc*32 + (lane >> 4)*8;
    ushort_t v[8];
#pragma unroll
    for (int j = 0; j < 8; ++j)
        v[j] = f2bf(W[(size_t)(o*C3 + ic0 + j)*9 + tap]);
    *(int4*)(Wpk + (size_t)k*8) = *(const int4*)v;
}

// ===========================================================================
// conv v4: producer-consumer implicit-GEMM bf16 MFMA.
// Reads planar feat (256 B/pixel, ch 0..127) + xcl (128 B/pixel, ch 128..191).
// Block = (b, y-pair), 512 threads = 8 waves: 6 compute + 2 produce.
// ===========================================================================
__global__ __launch_bounds__(512, 2) void conv_mfma(
    const ushort_t* __restrict__ feat, const ushort_t* __restrict__ xcl,
    const ushort_t* __restrict__ Wpk,
    const float* __restrict__ bias, const float* __restrict__ gamma,
    const float* __restrict__ beta, const float* __restrict__ mean,
    const float* __restrict__ var,  float* __restrict__ out)
{
    __shared__ ushort_t sA[2*CBUF];            // 133,120 B

    const int t = threadIdx.x;
    const int wv = t >> 6, lane = t & 63;
    const int m = lane & 15, quad = lane >> 4;
    const int b  = blockIdx.x >> 6, y0 = (blockIdx.x & 63)*2;
    const int yi = wv & 1, og = wv >> 1;       // compute waves: og 0..2

    f32x4 acc[32];                              // [j][xt] -> acc[j*8+xt]
#pragma unroll
    for (int i = 0; i < 32; ++i) acc[i] = (f32x4){0.f,0.f,0.f,0.f};

    // ---- producer: stage 64-c chunk into buffer (4160 16B slots, 128 lanes)
    auto produce = [&](int ch, int bufi) {
        ushort_t* dst = sA + bufi*CBUF;
        const ushort_t* base = (ch < 2) ? feat : xcl;
        const int ps = (ch < 2) ? 128 : 64;
        const int co = (ch == 1) ? 64 : 0;
        const int pt = t - 384;                // wave 6 -> 0..63, wave 7 -> 64..127
        for (int i = 0; i < 32; ++i) {
            int sl = i*128 + pt;
            int wi = sl & 7, rowgx = sl >> 3;
            int row = rowgx / PW, gx = rowgx - row*PW;
            int wl = wi ^ (gx & 7);            // granule swizzle (global side)
            const ushort_t* g = base + (((size_t)b*PW + y0 + row)*PW + gx)*ps
                                     + co + wl*8;
            __builtin_amdgcn_global_load_lds(
                (const __attribute__((address_space(1))) unsigned int*)g,
                (__attribute__((address_space(3))) unsigned int*)(dst + (size_t)sl*8),
                16, 0, 0);
        }
        if (pt < 64) {
            int sl = 4096 + pt;
            int wi = sl & 7, rowgx = sl >> 3;
            int row = rowgx / PW, gx = rowgx - row*PW;
            int wl = wi ^ (gx & 7);
            const ushort_t* g = base + (((size_t)b*PW + y0 + row)*PW + gx)*ps
                                     + co + wl*8;
            __builtin_amdgcn_global_load_lds(
                (const __attribute__((address_space(1))) unsigned int*)g,
                (__attribute__((address_space(3))) unsigned int*)(dst + (size_t)sl*8),
                16, 0, 0);
        }
    };

    // ---- consumer: one 64-c chunk = 9 taps x 8 xt x 2 k x 4 o-tiles ----
    auto compute = [&](int ch, int bufi) {
        const ushort_t* src = sA + bufi*CBUF;
        short8 bf[8], bfn[8];
#pragma unroll
        for (int j = 0; j < 4; ++j)
#pragma unroll
            for (int k = 0; k < 2; ++k)
                bf[j*2+k] = *(const short8*)(Wpk +
                    (((size_t)(og*4+j)*54 + ch*2 + k)*64 + lane)*8);
#pragma unroll
        for (int tap = 0; tap < 9; ++tap) {
            if (tap < 8) {
#pragma unroll
                for (int j = 0; j < 4; ++j)
#pragma unroll
                    for (int k = 0; k < 2; ++k)
                        bfn[j*2+k] = *(const short8*)(Wpk +
                            (((size_t)(og*4+j)*54 + (tap+1)*6 + ch*2 + k)*64 + lane)*8);
            }
            const int ky = tap/3, kx = tap - ky*3;
            const int sw = (kx + m) & 7;
            const int rowb = ((yi + ky)*PW + kx + m)*64;
            const int g0 = (quad ^ sw)*8, g1 = ((quad+4) ^ sw)*8;
#pragma unroll
            for (int xt = 0; xt < 8; ++xt) {
                short8 af0 = *(const short8*)(src + rowb + xt*1024 + g0);
                short8 af1 = *(const short8*)(src + rowb + xt*1024 + g1);
#pragma unroll
                for (int j = 0; j < 4; ++j) {
                    acc[j*8+xt] = __builtin_amdgcn_mfma_f32_16x16x32_bf16(af0, bf[j*2],   acc[j*8+xt], 0,0,0);
                    acc[j*8+xt] = __builtin_amdgcn_mfma_f32_16x16x32_bf16(af1, bf[j*2+1], acc[j*8+xt], 0,0,0);
                }
            }
#pragma unroll
            for (int q = 0; q < 8; ++q) bf[q] = bfn[q];
        }
    };

    // ---- pipeline: 3 chunks of 64 c, producers one chunk ahead ----
    if (wv >= 6) produce(0, 0);
    __syncthreads();
    for (int ch = 0; ch < 3; ++ch) {
        if (wv >= 6) { if (ch < 2) produce(ch + 1, (ch + 1) & 1); }
        else          compute(ch, ch & 1);
        __syncthreads();
    }

    // ---- epilogue: BN+ReLU -> LDS stage -> full-line stores ----
    float* sOut = (float*)sA;                  // 192 x 132 f32 = 101,376 B
    for (int y = 0; y < 2; ++y) {
        if (wv < 6 && yi == y) {
#pragma unroll
            for (int j = 0; j < 4; ++j) {
                int o = (og*4 + j)*16 + m;
                float A  = gamma[o] * rsqrtf(var[o] + 1e-4f);
                float Bv = (bias[o] - mean[o])*A + beta[o];
#pragma unroll
                for (int xt = 0; xt < 8; ++xt) {
                    f32x4 a4 = acc[j*8 + xt];
                    *(float4*)(sOut + o*132 + xt*16 + quad*4) =
                        make_float4(fmaxf(a4[0]*A + Bv, 0.f), fmaxf(a4[1]*A + Bv, 0.f),
                                    fmaxf(a4[2]*A + Bv, 0.f), fmaxf(a4[3]*A + Bv, 0.f));
                }
            }
        }
        __syncthreads();
#pragma unroll
        for (int i = 0; i < 12; ++i) {
            int s = i*512 + t;                 // 6144 float4 slots
            int o = s >> 5, xs4 = (s & 31)*4;
            float4 v = *(const float4*)(sOut + o*132 + xs4);
            *(float4*)(out + (((size_t)b*C3 + o)*H + y0 + y)*WD + xs4) = v;
        }
        __syncthreads();
    }
}

extern "C" void kernel_launch(void* const* d_in, const int* in_sizes, int n_in,
                              void* d_out, int out_size, void* d_ws, size_t ws_size,
                              hipStream_t stream)
{
    const float* x   = (const float*)d_in[0];
    const float* xf  = (const float*)d_in[1];
    const float* xr  = (const float*)d_in[2];
    const float* Wx  = (const float*)d_in[3];
    const float* bx  = (const float*)d_in[4];
    const float* Wx1 = (const float*)d_in[5];
    const float* bx1 = (const float*)d_in[6];
    const float* Wx2 = (const float*)d_in[7];
    const float* bx2 = (const float*)d_in[8];
    const float* Wxf = (const float*)d_in[9];
    const float* bxf = (const float*)d_in[10];
    const float* Wxr = (const float*)d_in[11];
    const float* bxr = (const float*)d_in[12];
    const float* Wm  = (const float*)d_in[13];
    const float* bms = (const float*)d_in[14];
    const float* gam = (const float*)d_in[15];
    const float* bet = (const float*)d_in[16];
    const float* mea = (const float*)d_in[17];
    const float* va  = (const float*)d_in[18];
    (void)in_sizes; (void)n_in; (void)out_size; (void)ws_size;

    // ws layout (bytes):
    //   feat (B,PW,PW,128) bf16 @ 0            (34,611,200)
    //   xcl  (B,PW,PW,64)  bf16 @ 34,611,200   (17,305,600)  -> ends 51,916,800
    //   Wpk  @ 51,916,800  (663,552)           -> ends 52,580,352
    //   Wall @ 52,700,000  (40,960); ball @ 52,750,000 (1,280)
    // xfT/xrT scratch live in d_out (fully overwritten by conv afterwards):
    //   xfT @ d_out+0 (16,777,216), xrT @ d_out+16,777,216 (16,777,216)
    ushort_t* feat = (ushort_t*)d_ws;
    ushort_t* xcl  = (ushort_t*)((char*)d_ws + 34611200);
    ushort_t* Wpk  = (ushort_t*)((char*)d_ws + 51916800);
    ushort_t* Wall = (ushort_t*)((char*)d_ws + 52700000);
    float*    ball = (float*)   ((char*)d_ws + 52750000);
    ushort_t* xfT  = (ushort_t*)d_out;
    ushort_t* xrT  = (ushort_t*)((char*)d_out + 16777216);
    float* outp = (float*)d_out;

    compose_kernel<<<dim3(64), dim3(64), 0, stream>>>(
        Wx, bx, Wx1, bx1, Wx2, bx2, Wxf, bxf, Wxr, bxr, Wall, ball);
    pack_kernel<<<dim3(162), dim3(256), 0, stream>>>(Wm, Wpk);
    prep_kernel<<<dim3(BATCH*PW), dim3(256), 0, stream>>>(
        x, xf, xr, xcl, feat, xfT, xrT);
    attn_mfma<<<dim3(BATCH*H), dim3(256), 0, stream>>>(
        xcl, xfT, xrT, Wall, ball, feat);
    conv_mfma<<<dim3(BATCH*64), dim3(512), 0, stream>>>(
        feat, xcl, Wpk, bms, gam, bet, mea, va, outp);
}